// Round 7
// baseline (513.363 us; speedup 1.0000x reference)
//
#include <hip/hip_runtime.h>
#include <hip/hip_bf16.h>
#include <stdint.h>

// Problem constants (B=2, S=4096, F=512, H=8, D=64)
#define NB 2
#define NS 4096
#define NF 512
#define NH 8
#define ND 64
#define NM (NB * NS)  // 8192 rows for all projections
#define NROW (NB * NH * NS)  // 65536 (b,h,s) rows

typedef __attribute__((ext_vector_type(8))) short bf16x8;
typedef __attribute__((ext_vector_type(4))) float f32x4;
typedef __attribute__((ext_vector_type(16))) float f32x16;

static __device__ __forceinline__ unsigned short f2bf(float f) {
    union { float f; uint32_t u; } x; x.f = f;
    uint32_t u = x.u;
    u += 0x7FFFu + ((u >> 16) & 1u);  // RNE
    return (unsigned short)(u >> 16);
}
static __device__ __forceinline__ float bf2f(unsigned short u) {
    union { uint32_t u; float f; } x; x.u = ((uint32_t)u) << 16;
    return x.f;
}
// packed f32x2 -> bf16x2 (1 instr vs ~8; no builtin on gfx950)
static __device__ __forceinline__ unsigned int cvtpk(float lo, float hi) {
    unsigned int r;
    asm("v_cvt_pk_bf16_f32 %0, %1, %2" : "=v"(r) : "v"(lo), "v"(hi));
    return r;
}

// global -> LDS direct (width 16). LDS dest is wave-uniform base; HW adds lane*16.
static __device__ __forceinline__ void load_lds16(const void* g, void* l) {
    __builtin_amdgcn_global_load_lds(
        (const __attribute__((address_space(1))) void*)g,
        (__attribute__((address_space(3))) void*)l,
        16, 0, 0);
}

// ---------------------------------------------------------------------------
// fp32 -> bf16 conversion: activations (q,k,v) vectorized + weight transposes.
// Weight loop decodes OUTPUT-major so the bf16 writes are coalesced; the
// strided fp32 reads are L2-absorbed (4 MB of weights, read once each).
__global__ void convert_all(const float* __restrict__ q, const float* __restrict__ k,
                            const float* __restrict__ v,
                            unsigned short* __restrict__ qb, unsigned short* __restrict__ kb,
                            unsigned short* __restrict__ vb,
                            const float* __restrict__ wq, const float* __restrict__ wk,
                            const float* __restrict__ wv, const float* __restrict__ wo,
                            unsigned short* __restrict__ o0, unsigned short* __restrict__ o1,
                            unsigned short* __restrict__ o2, unsigned short* __restrict__ o3) {
    int i0 = blockIdx.x * blockDim.x + threadIdx.x;
    int stride = gridDim.x * blockDim.x;
    const int n4 = (NB * NS * NF) / 4;
    for (int i = i0; i < n4; i += stride) {
        float4 a = ((const float4*)q)[i];
        float4 b = ((const float4*)k)[i];
        float4 c = ((const float4*)v)[i];
        ushort4 oa, ob, oc;
        oa.x = f2bf(a.x); oa.y = f2bf(a.y); oa.z = f2bf(a.z); oa.w = f2bf(a.w);
        ob.x = f2bf(b.x); ob.y = f2bf(b.y); ob.z = f2bf(b.z); ob.w = f2bf(b.w);
        oc.x = f2bf(c.x); oc.y = f2bf(c.y); oc.z = f2bf(c.z); oc.w = f2bf(c.w);
        ((ushort4*)qb)[i] = oa;
        ((ushort4*)kb)[i] = ob;
        ((ushort4*)vb)[i] = oc;
    }
    // weights: WT[n][kq] = W[kq][n]; j output-major -> coalesced 2B writes
    for (int j = i0; j < 4 * NF * NF; j += stride) {
        int w = j >> 18;
        int off = j & (NF * NF - 1);
        int n = off >> 9;         // output row
        int kq = off & (NF - 1);  // output col (fast) -> write coalesced
        const float* src = (w == 0) ? wq : (w == 1) ? wk : (w == 2) ? wv : wo;
        unsigned short* dst = (w == 0) ? o0 : (w == 1) ? o1 : (w == 2) ? o2 : o3;
        dst[off] = f2bf(src[kq * NF + n]);
    }
}

// ---------------------------------------------------------------------------
// Merged Q/K/V projection, 2-phase double-buffered. 128x128 tile, BK=64,
// 4 waves. blockIdx.z: 0=Q (scale (1/8)*log2(e) for exp2-domain softmax,
// out [B,H,S,D]), 1=K ([B,H,S,D]), 2=V (out transposed [B,H,D,S]).
__launch_bounds__(256, 2)
__global__ void proj_qkv(const unsigned short* __restrict__ Aq,
                         const unsigned short* __restrict__ Ak,
                         const unsigned short* __restrict__ Av,
                         const unsigned short* __restrict__ WqT,
                         const unsigned short* __restrict__ WkT,
                         const unsigned short* __restrict__ WvT,
                         const float* __restrict__ bq, const float* __restrict__ bk,
                         const float* __restrict__ bv,
                         unsigned short* __restrict__ Qh, unsigned short* __restrict__ Kh,
                         unsigned short* __restrict__ VTs) {
    __shared__ char smem[65536];  // 2 bufs x (A 16KB | B 16KB)

    const int mode = blockIdx.z;
    const unsigned short* A  = (mode == 0) ? Aq : (mode == 1) ? Ak : Av;
    const unsigned short* WT = (mode == 0) ? WqT : (mode == 1) ? WkT : WvT;
    const float* bias        = (mode == 0) ? bq : (mode == 1) ? bk : bv;

    const int t = threadIdx.x;
    const int wid = t >> 6;
    const int lane = t & 63;
    const int l15 = lane & 15;
    const int lhi = lane >> 4;
    const int m0 = blockIdx.x * 128;
    const int n0 = blockIdx.y * 128;
    const int wm = (wid >> 1) * 64;
    const int wn = (wid & 1) * 64;

    const int srow = t >> 3;
    const int scol = ((t & 7) * 16) ^ ((srow & 7) << 4);

    const f32x4 zero4 = {0.f, 0.f, 0.f, 0.f};
    f32x4 acc[4][4];
#pragma unroll
    for (int i = 0; i < 4; ++i)
#pragma unroll
        for (int j = 0; j < 4; ++j) acc[i][j] = zero4;

    auto STAGE = [&](int buf, int k0) {
        char* As = smem + buf * 32768;
        char* Bs = As + 16384;
#pragma unroll
        for (int i = 0; i < 4; ++i) {
            const char* sa = (const char*)A + ((size_t)(m0 + i * 32 + srow) * NF + k0) * 2 + scol;
            load_lds16(sa, As + i * 4096 + wid * 1024);
            const char* sb = (const char*)WT + ((size_t)(n0 + i * 32 + srow) * NF + k0) * 2 + scol;
            load_lds16(sb, Bs + i * 4096 + wid * 1024);
        }
    };

    STAGE(0, 0);
    int cur = 0;
    for (int kt = 0; kt < 8; ++kt) {
        if (kt < 7) {
            STAGE(cur ^ 1, (kt + 1) * 64);  // prefetch next tile (8 loads/thread)
            asm volatile("s_waitcnt vmcnt(8)" ::: "memory");  // current tile landed
        } else {
            asm volatile("s_waitcnt vmcnt(0)" ::: "memory");
        }
        __builtin_amdgcn_s_barrier();
        __builtin_amdgcn_sched_barrier(0);

        const char* As = smem + cur * 32768;
        const char* Bs = As + 16384;
#pragma unroll
        for (int ks = 0; ks < 2; ++ks) {
            bf16x8 af[4], bfr[4];
#pragma unroll
            for (int i = 0; i < 4; ++i) {
                int ra = wm + i * 16 + l15;
                int ca = (ks * 64 + lhi * 16) ^ ((ra & 7) << 4);
                af[i] = *(const bf16x8*)(As + ra * 128 + ca);
                int rb = wn + i * 16 + l15;
                int cb = (ks * 64 + lhi * 16) ^ ((rb & 7) << 4);
                bfr[i] = *(const bf16x8*)(Bs + rb * 128 + cb);
            }
#pragma unroll
            for (int mi = 0; mi < 4; ++mi)
#pragma unroll
                for (int ni = 0; ni < 4; ++ni)
                    acc[mi][ni] = __builtin_amdgcn_mfma_f32_16x16x32_bf16(af[mi], bfr[ni], acc[mi][ni], 0, 0, 0);
        }
        __builtin_amdgcn_sched_barrier(0);
        __builtin_amdgcn_s_barrier();  // reads done before next overwrite
        cur ^= 1;
    }

    // epilogue: C/D layout col = lane&15, row = (lane>>4)*4 + reg
#pragma unroll
    for (int ni = 0; ni < 4; ++ni) {
        int col = n0 + wn + ni * 16 + l15;
        float bv2 = bias[col];
#pragma unroll
        for (int mi = 0; mi < 4; ++mi) {
#pragma unroll
            for (int r = 0; r < 4; ++r) {
                int row = m0 + wm + mi * 16 + lhi * 4 + r;
                float val = acc[mi][ni][r] + bv2;
                int b = row >> 12, s = row & (NS - 1);
                int hh = col >> 6, d = col & (ND - 1);
                if (mode == 0) {
                    val *= 0.1803368801111244f;  // (1/8) * log2(e): exp2-domain
                    Qh[((size_t)(b * NH + hh) * NS + s) * ND + d] = f2bf(val);
                } else if (mode == 1) {
                    Kh[((size_t)(b * NH + hh) * NS + s) * ND + d] = f2bf(val);
                } else {  // V transposed: [B,H,D,S]
                    VTs[((size_t)(b * NH + hh) * ND + d) * NS + s] = f2bf(val);
                }
            }
        }
    }
}

// Output projection: fp32 out, row-major [8192,512]. 64x128 tile (512 blocks),
// 2-phase double-buffered.
__launch_bounds__(256, 2)
__global__ void proj_o(const unsigned short* __restrict__ A,
                       const unsigned short* __restrict__ WT,
                       const float* __restrict__ bias,
                       float* __restrict__ Out) {
    __shared__ char smem[49152];  // 2 bufs x (A 8KB | B 16KB)

    const int t = threadIdx.x;
    const int wid = t >> 6;
    const int lane = t & 63;
    const int l15 = lane & 15;
    const int lhi = lane >> 4;
    const int m0 = blockIdx.x * 64;
    const int n0 = blockIdx.y * 128;
    const int wm = (wid >> 1) * 32;
    const int wn = (wid & 1) * 64;

    const int srow = t >> 3;
    const int scol = ((t & 7) * 16) ^ ((srow & 7) << 4);

    const f32x4 zero4 = {0.f, 0.f, 0.f, 0.f};
    f32x4 acc[2][4];
#pragma unroll
    for (int i = 0; i < 2; ++i)
#pragma unroll
        for (int j = 0; j < 4; ++j) acc[i][j] = zero4;

    auto STAGE = [&](int buf, int k0) {
        char* As = smem + buf * 24576;
        char* Bs = As + 8192;
#pragma unroll
        for (int i = 0; i < 2; ++i) {
            const char* sa = (const char*)A + ((size_t)(m0 + i * 32 + srow) * NF + k0) * 2 + scol;
            load_lds16(sa, As + i * 4096 + wid * 1024);
        }
#pragma unroll
        for (int i = 0; i < 4; ++i) {
            const char* sb = (const char*)WT + ((size_t)(n0 + i * 32 + srow) * NF + k0) * 2 + scol;
            load_lds16(sb, Bs + i * 4096 + wid * 1024);
        }
    };

    STAGE(0, 0);
    int cur = 0;
    for (int kt = 0; kt < 8; ++kt) {
        if (kt < 7) {
            STAGE(cur ^ 1, (kt + 1) * 64);  // 6 loads/thread
            asm volatile("s_waitcnt vmcnt(6)" ::: "memory");
        } else {
            asm volatile("s_waitcnt vmcnt(0)" ::: "memory");
        }
        __builtin_amdgcn_s_barrier();
        __builtin_amdgcn_sched_barrier(0);

        const char* As = smem + cur * 24576;
        const char* Bs = As + 8192;
#pragma unroll
        for (int ks = 0; ks < 2; ++ks) {
            bf16x8 af[2], bfr[4];
#pragma unroll
            for (int i = 0; i < 2; ++i) {
                int ra = wm + i * 16 + l15;
                int ca = (ks * 64 + lhi * 16) ^ ((ra & 7) << 4);
                af[i] = *(const bf16x8*)(As + ra * 128 + ca);
            }
#pragma unroll
            for (int i = 0; i < 4; ++i) {
                int rb = wn + i * 16 + l15;
                int cb = (ks * 64 + lhi * 16) ^ ((rb & 7) << 4);
                bfr[i] = *(const bf16x8*)(Bs + rb * 128 + cb);
            }
#pragma unroll
            for (int mi = 0; mi < 2; ++mi)
#pragma unroll
                for (int ni = 0; ni < 4; ++ni)
                    acc[mi][ni] = __builtin_amdgcn_mfma_f32_16x16x32_bf16(af[mi], bfr[ni], acc[mi][ni], 0, 0, 0);
        }
        __builtin_amdgcn_sched_barrier(0);
        __builtin_amdgcn_s_barrier();
        cur ^= 1;
    }

#pragma unroll
    for (int ni = 0; ni < 4; ++ni) {
        int col = n0 + wn + ni * 16 + l15;
        float bv2 = bias[col];
#pragma unroll
        for (int mi = 0; mi < 2; ++mi)
#pragma unroll
            for (int r = 0; r < 4; ++r) {
                int row = m0 + wm + mi * 16 + lhi * 4 + r;
                Out[(size_t)row * NF + col] = acc[mi][ni][r] + bv2;
            }
    }
}

// ---------------------------------------------------------------------------
// Fused causal flash attention — split-K (2 KV-halves per q-group), barrier-
// free, exp2-domain softmax. One WAVE per block (64 thr). 4096 blocks:
// k = blockIdx.x; pr = k&1 (KV half), kk = k>>1: bh = kk&15, g = 127-(kk>>4)
// (heavy-first). Wave owns 32 q rows, processes tiles [tbeg,tend) of 64 kv.
// Partials (m log2-domain, l, O bf16) -> workspace; attn_combine merges.
// S^T = mfma(A=K, B=Q): D col = q = lane&31; row = kv = (r&3)+8*(r>>2)+4*h.
// P in registers (cvt_pk_bf16 pack + half-swap exchange -> PV B-fragments).
// O^T = mfma(A=V^T, B=P^T) with V pre-transposed [B,H,D,S].
__launch_bounds__(64, 4)
__global__ void attn_fused(const unsigned short* __restrict__ Qh,
                           const unsigned short* __restrict__ Kh,
                           const unsigned short* __restrict__ VT,
                           unsigned short* __restrict__ Op,   // [2][NROW][64] bf16
                           float* __restrict__ Mp,            // [2][NROW]
                           float* __restrict__ Lp) {          // [2][NROW]
    const int lane = threadIdx.x;  // 0..63
    const int l31 = lane & 31;
    const int h = lane >> 5;
    const int k = blockIdx.x;
    const int pr = k & 1;
    const int kk = k >> 1;
    const int bh = kk & 15;
    const int g = 127 - (kk >> 4);  // q-group (32 rows), heavy-first
    const int b = bh >> 3, hh = bh & 7;
    const size_t bhs = (size_t)b * NH + hh;
    const char* Qp = (const char*)(Qh + bhs * NS * ND);
    const char* Kp = (const char*)(Kh + bhs * NS * ND);
    const char* Vp = (const char*)(VT + bhs * (size_t)ND * NS);

    // Q fragments (B operand): Q[q=l31][16*kc + 8*h + j], contiguous 16B
    const int qrow = g * 32 + l31;
    bf16x8 qf[4];
#pragma unroll
    for (int kc = 0; kc < 4; ++kc)
        qf[kc] = *(const bf16x8*)(Qp + (size_t)qrow * 128 + kc * 32 + h * 16);

    f32x16 o[2];
#pragma unroll
    for (int r = 0; r < 16; ++r) { o[0][r] = 0.f; o[1][r] = 0.f; }
    float m_run = -1e30f, l_run = 0.f;

    const int nkv = (g >> 1) + 1;        // total KV tiles for this q-group
    const int hsp = (nkv + 1) >> 1;      // split point
    const int tbeg = pr ? hsp : 0;
    const int tend = pr ? nkv : hsp;

    // K fragments (A operand): kf[kvi*4+kc] = K[kv0+kvi*32+l31][kc*16+8h+:8]
    auto LOADK = [&](int t, bf16x8* kf) {
        const char* base = Kp + (size_t)t * 64 * 128;
#pragma unroll
        for (int kvi = 0; kvi < 2; ++kvi)
#pragma unroll
            for (int kc = 0; kc < 4; ++kc)
                kf[kvi * 4 + kc] = *(const bf16x8*)(base + (kvi * 32 + l31) * 128 + kc * 32 + h * 16);
    };
    // V fragments (A operand): vf[di*4+ck] = V^T[di*32+l31][kv0+ck*16+8h+:8]
    auto LOADV = [&](int t, bf16x8* vf) {
        const char* base = Vp + (size_t)t * 128;
#pragma unroll
        for (int di = 0; di < 2; ++di)
#pragma unroll
            for (int ck = 0; ck < 4; ++ck)
                vf[di * 4 + ck] = *(const bf16x8*)(base + (size_t)(di * 32 + l31) * (NS * 2) + ck * 32 + h * 16);
    };

    auto TILE = [&](int t, const bf16x8* kf, const bf16x8* vf) {
        // S^T = K @ Q^T (log2-domain scores: Q pre-scaled by log2e/8)
        f32x16 sT[2];
#pragma unroll
        for (int r = 0; r < 16; ++r) { sT[0][r] = 0.f; sT[1][r] = 0.f; }
#pragma unroll
        for (int kvi = 0; kvi < 2; ++kvi)
#pragma unroll
            for (int kc = 0; kc < 4; ++kc)
                sT[kvi] = __builtin_amdgcn_mfma_f32_32x32x16_bf16(kf[kvi * 4 + kc], qf[kc], sT[kvi], 0, 0, 0);

        // causal mask (the globally-last tile holds every row's diagonal)
        if (t == nkv - 1) {
#pragma unroll
            for (int kvi = 0; kvi < 2; ++kvi)
#pragma unroll
                for (int r = 0; r < 16; ++r) {
                    int kv = t * 64 + kvi * 32 + (r & 3) + ((r >> 2) << 3) + h * 4;
                    if (kv > qrow) sT[kvi][r] = -1e30f;
                }
        }

        // online softmax (base-2): lane owns one q; partner (xor 32) other 32 kv
        float pm = -1e30f;
#pragma unroll
        for (int kvi = 0; kvi < 2; ++kvi)
#pragma unroll
            for (int r = 0; r < 16; ++r) pm = fmaxf(pm, sT[kvi][r]);
        pm = fmaxf(pm, __shfl_xor(pm, 32));

        if (__ballot(pm > m_run + 11.5f) != 0ull) {  // defer-max (8 nats in bits)
            float mnew = fmaxf(m_run, pm);
            float sc = __builtin_amdgcn_exp2f(m_run - mnew);
            m_run = mnew;
            l_run *= sc;
#pragma unroll
            for (int di = 0; di < 2; ++di)
#pragma unroll
                for (int r = 0; r < 16; ++r) o[di][r] *= sc;
        }
        float rs = 0.f;
#pragma unroll
        for (int kvi = 0; kvi < 2; ++kvi)
#pragma unroll
            for (int r = 0; r < 16; ++r) {
                float p = __builtin_amdgcn_exp2f(sT[kvi][r] - m_run);
                sT[kvi][r] = p;
                rs += p;
            }
        rs += __shfl_xor(rs, 32);
        l_run += rs;

        // pack P via v_cvt_pk_bf16_f32; w[kvi][i] covers kv pair base
        // kvi*32 + 2*(i&1) + 8*(i>>1) + 4*h
        unsigned int w[2][8];
#pragma unroll
        for (int kvi = 0; kvi < 2; ++kvi)
#pragma unroll
            for (int i = 0; i < 8; ++i)
                w[kvi][i] = cvtpk(sT[kvi][2 * i], sT[kvi][2 * i + 1]);

        // exchange halves -> pf[ck]: element j = P[q=own][kv=16ck+8h+j];
        // each side CONTRIBUTES the word the other needs (value-select)
        union FB { unsigned int u[4]; bf16x8 v; };
        bf16x8 pf[4];
#pragma unroll
        for (int ck = 0; ck < 4; ++ck) {
            const int kvi = ck >> 1, pb = (ck & 1) * 4;
            unsigned int aSrc = h ? w[kvi][pb + 0] : w[kvi][pb + 2];
            unsigned int bSrc = h ? w[kvi][pb + 1] : w[kvi][pb + 3];
            unsigned int sA = (unsigned int)__shfl_xor((int)aSrc, 32);
            unsigned int sB = (unsigned int)__shfl_xor((int)bSrc, 32);
            FB f;
            f.u[0] = (h == 0) ? w[kvi][pb + 0] : sA;
            f.u[1] = (h == 0) ? w[kvi][pb + 1] : sB;
            f.u[2] = (h == 0) ? sA : w[kvi][pb + 2];
            f.u[3] = (h == 0) ? sB : w[kvi][pb + 3];
            pf[ck] = f.v;
        }

        // O^T += V^T @ P^T
#pragma unroll
        for (int di = 0; di < 2; ++di)
#pragma unroll
            for (int ck = 0; ck < 4; ++ck)
                o[di] = __builtin_amdgcn_mfma_f32_32x32x16_bf16(vf[di * 4 + ck], pf[ck], o[di], 0, 0, 0);
    };

    // ping-pong K sets (no runtime-indexed register arrays), JIT V
    if (tbeg < tend) {
        bf16x8 kA[8], kB[8], vv[8];
        LOADK(tbeg, kA);
        int t = tbeg;
        while (true) {
            LOADV(t, vv);
            if (t + 1 < tend) LOADK(t + 1, kB);
            TILE(t, kA, vv);
            if (++t >= tend) break;
            LOADV(t, vv);
            if (t + 1 < tend) LOADK(t + 1, kA);
            TILE(t, kB, vv);
            if (++t >= tend) break;
        }
    }

    // store partials: O bf16 (lane's d = 32*di + 8*tq + 4*h + r), m, l
    const int prow = bh * NS + qrow;
    size_t pb = ((size_t)pr * NROW + prow) * 64;
#pragma unroll
    for (int di = 0; di < 2; ++di)
#pragma unroll
        for (int tq = 0; tq < 4; ++tq) {
            uint2 pk;
            pk.x = cvtpk(o[di][4 * tq + 0], o[di][4 * tq + 1]);
            pk.y = cvtpk(o[di][4 * tq + 2], o[di][4 * tq + 3]);
            *(uint2*)(Op + pb + di * 32 + tq * 8 + h * 4) = pk;
        }
    if (h == 0) {
        Mp[pr * NROW + prow] = m_run;
        Lp[pr * NROW + prow] = l_run;
    }
}

// Merge the two KV-half partials: out = (O0*e0 + O1*e1) / (l0*e0 + l1*e1),
// e_i = exp2(m_i - max(m0,m1)). Writes concat [B,S,F] bf16. 1M threads x4 d.
__global__ void attn_combine(const unsigned short* __restrict__ Op,
                             const float* __restrict__ Mp, const float* __restrict__ Lp,
                             unsigned short* __restrict__ Cc) {
    int i = blockIdx.x * blockDim.x + threadIdx.x;  // NROW*16
    int row = i >> 4;
    int d4 = (i & 15) << 2;
    float m0 = Mp[row], m1 = Mp[NROW + row];
    float l0 = Lp[row], l1 = Lp[NROW + row];
    float m = fmaxf(m0, m1);
    float e0 = __builtin_amdgcn_exp2f(m0 - m);
    float e1 = __builtin_amdgcn_exp2f(m1 - m);
    float inv = 1.0f / (l0 * e0 + l1 * e1);
    e0 *= inv; e1 *= inv;
    ushort4 a = *(const ushort4*)(Op + (size_t)row * 64 + d4);
    ushort4 c = *(const ushort4*)(Op + (size_t)NROW * 64 + (size_t)row * 64 + d4);
    ushort4 r;
    r.x = f2bf(bf2f(a.x) * e0 + bf2f(c.x) * e1);
    r.y = f2bf(bf2f(a.y) * e0 + bf2f(c.y) * e1);
    r.z = f2bf(bf2f(a.z) * e0 + bf2f(c.z) * e1);
    r.w = f2bf(bf2f(a.w) * e0 + bf2f(c.w) * e1);
    int bb = row >> 15, hh = (row >> 12) & 7, s = row & (NS - 1);
    *(ushort4*)(Cc + ((size_t)(bb * NS + s) * NF) + hh * ND + d4) = r;
}

// ---------------------------------------------------------------------------
extern "C" void kernel_launch(void* const* d_in, const int* in_sizes, int n_in,
                              void* d_out, int out_size, void* d_ws, size_t ws_size,
                              hipStream_t stream) {
    const float* q = (const float*)d_in[0];
    const float* k = (const float*)d_in[1];
    const float* v = (const float*)d_in[2];
    // d_in[3] = mask (deterministic causal; applied analytically)
    const float* wq = (const float*)d_in[4];
    const float* bq = (const float*)d_in[5];
    const float* wk = (const float*)d_in[6];
    const float* bk = (const float*)d_in[7];
    const float* wv = (const float*)d_in[8];
    const float* bv = (const float*)d_in[9];
    const float* wo = (const float*)d_in[10];
    const float* bo = (const float*)d_in[11];

    const size_t MB = 1u << 20;
    char* ws = (char*)d_ws;
    unsigned short* qb  = (unsigned short*)(ws);             // 8MB (reused as concat)
    unsigned short* kb  = (unsigned short*)(ws + 8 * MB);    // 8MB  } reused as Opart
    unsigned short* vb  = (unsigned short*)(ws + 16 * MB);   // 8MB  } (16MB, 2xNROWx64 bf16)
    unsigned short* wqT = (unsigned short*)(ws + 24 * MB);           // } reused as Mp/Lp
    unsigned short* wkT = (unsigned short*)(ws + 24 * MB + 512 * 1024);
    unsigned short* wvT = (unsigned short*)(ws + 25 * MB);
    unsigned short* woT = (unsigned short*)(ws + 25 * MB + 512 * 1024);  // kept for proj_o
    unsigned short* Qh  = (unsigned short*)(ws + 26 * MB);   // 8MB [B,H,S,D] pre-scaled
    unsigned short* Kh  = (unsigned short*)(ws + 34 * MB);   // 8MB [B,H,S,D]
    unsigned short* VTs = (unsigned short*)(ws + 42 * MB);   // 8MB [B,H,D,S]

    unsigned short* Opart = kb;                        // 16MB, dead kb+vb
    float* Mpart = (float*)(ws + 24 * MB);             // 512KB over dead wqT
    float* Lpart = (float*)(ws + 24 * MB + 512 * 1024);// 512KB over dead wkT

    convert_all<<<dim3(2048), dim3(256), 0, stream>>>(q, k, v, qb, kb, vb,
                                                      wq, wk, wv, wo, wqT, wkT, wvT, woT);

    proj_qkv<<<dim3(NM / 128, NF / 128, 3), dim3(256), 0, stream>>>(
        qb, kb, vb, wqT, wkT, wvT, bq, bk, bv, Qh, Kh, VTs);

    attn_fused<<<dim3(4096), dim3(64), 0, stream>>>(Qh, Kh, VTs, Opart, Mpart, Lpart);

    attn_combine<<<dim3(NROW * 16 / 256), dim3(256), 0, stream>>>(Opart, Mpart, Lpart, qb);

    proj_o<<<dim3(NM / 64, NF / 128), dim3(256), 0, stream>>>(qb, woT, bo, (float*)d_out);
}

// Round 8
// 324.988 us; speedup vs baseline: 1.5796x; 1.5796x over previous
//
#include <hip/hip_runtime.h>
#include <hip/hip_bf16.h>
#include <stdint.h>

// Problem constants (B=2, S=4096, F=512, H=8, D=64)
#define NB 2
#define NS 4096
#define NF 512
#define NH 8
#define ND 64
#define NM (NB * NS)  // 8192 rows for all projections
#define NROW (NB * NH * NS)  // 65536 (b,h,s) rows

typedef __attribute__((ext_vector_type(8))) short bf16x8;
typedef __attribute__((ext_vector_type(4))) float f32x4;
typedef __attribute__((ext_vector_type(16))) float f32x16;

static __device__ __forceinline__ unsigned short f2bf(float f) {
    union { float f; uint32_t u; } x; x.f = f;
    uint32_t u = x.u;
    u += 0x7FFFu + ((u >> 16) & 1u);  // RNE
    return (unsigned short)(u >> 16);
}
static __device__ __forceinline__ float bf2f(unsigned short u) {
    union { uint32_t u; float f; } x; x.u = ((uint32_t)u) << 16;
    return x.f;
}
// packed f32x2 -> bf16x2 (1 instr vs ~8; no builtin on gfx950)
static __device__ __forceinline__ unsigned int cvtpk(float lo, float hi) {
    unsigned int r;
    asm("v_cvt_pk_bf16_f32 %0, %1, %2" : "=v"(r) : "v"(lo), "v"(hi));
    return r;
}

// global -> LDS direct (width 16). LDS dest is wave-uniform base; HW adds lane*16.
static __device__ __forceinline__ void load_lds16(const void* g, void* l) {
    __builtin_amdgcn_global_load_lds(
        (const __attribute__((address_space(1))) void*)g,
        (__attribute__((address_space(3))) void*)l,
        16, 0, 0);
}

// ---------------------------------------------------------------------------
// fp32 -> bf16 conversion: activations (q,k,v) vectorized + weight transposes.
// Weight loop decodes OUTPUT-major so the bf16 writes are coalesced; the
// strided fp32 reads are L2-absorbed (4 MB of weights, read once each).
__global__ void convert_all(const float* __restrict__ q, const float* __restrict__ k,
                            const float* __restrict__ v,
                            unsigned short* __restrict__ qb, unsigned short* __restrict__ kb,
                            unsigned short* __restrict__ vb,
                            const float* __restrict__ wq, const float* __restrict__ wk,
                            const float* __restrict__ wv, const float* __restrict__ wo,
                            unsigned short* __restrict__ o0, unsigned short* __restrict__ o1,
                            unsigned short* __restrict__ o2, unsigned short* __restrict__ o3) {
    int i0 = blockIdx.x * blockDim.x + threadIdx.x;
    int stride = gridDim.x * blockDim.x;
    const int n4 = (NB * NS * NF) / 4;
    for (int i = i0; i < n4; i += stride) {
        float4 a = ((const float4*)q)[i];
        float4 b = ((const float4*)k)[i];
        float4 c = ((const float4*)v)[i];
        ushort4 oa, ob, oc;
        oa.x = f2bf(a.x); oa.y = f2bf(a.y); oa.z = f2bf(a.z); oa.w = f2bf(a.w);
        ob.x = f2bf(b.x); ob.y = f2bf(b.y); ob.z = f2bf(b.z); ob.w = f2bf(b.w);
        oc.x = f2bf(c.x); oc.y = f2bf(c.y); oc.z = f2bf(c.z); oc.w = f2bf(c.w);
        ((ushort4*)qb)[i] = oa;
        ((ushort4*)kb)[i] = ob;
        ((ushort4*)vb)[i] = oc;
    }
    // weights: WT[n][kq] = W[kq][n]; j output-major -> coalesced 2B writes
    for (int j = i0; j < 4 * NF * NF; j += stride) {
        int w = j >> 18;
        int off = j & (NF * NF - 1);
        int n = off >> 9;         // output row
        int kq = off & (NF - 1);  // output col (fast) -> write coalesced
        const float* src = (w == 0) ? wq : (w == 1) ? wk : (w == 2) ? wv : wo;
        unsigned short* dst = (w == 0) ? o0 : (w == 1) ? o1 : (w == 2) ? o2 : o3;
        dst[off] = f2bf(src[kq * NF + n]);
    }
}

// ---------------------------------------------------------------------------
// Merged Q/K/V projection, 2-phase double-buffered. 128x128 tile, BK=64,
// 4 waves. blockIdx.z: 0=Q (scale (1/8)*log2(e) for exp2-domain softmax,
// out [B,H,S,D]), 1=K ([B,H,S,D]), 2=V (out transposed [B,H,D,S]).
__launch_bounds__(256, 2)
__global__ void proj_qkv(const unsigned short* __restrict__ Aq,
                         const unsigned short* __restrict__ Ak,
                         const unsigned short* __restrict__ Av,
                         const unsigned short* __restrict__ WqT,
                         const unsigned short* __restrict__ WkT,
                         const unsigned short* __restrict__ WvT,
                         const float* __restrict__ bq, const float* __restrict__ bk,
                         const float* __restrict__ bv,
                         unsigned short* __restrict__ Qh, unsigned short* __restrict__ Kh,
                         unsigned short* __restrict__ VTs) {
    __shared__ char smem[65536];  // 2 bufs x (A 16KB | B 16KB)

    const int mode = blockIdx.z;
    const unsigned short* A  = (mode == 0) ? Aq : (mode == 1) ? Ak : Av;
    const unsigned short* WT = (mode == 0) ? WqT : (mode == 1) ? WkT : WvT;
    const float* bias        = (mode == 0) ? bq : (mode == 1) ? bk : bv;

    const int t = threadIdx.x;
    const int wid = t >> 6;
    const int lane = t & 63;
    const int l15 = lane & 15;
    const int lhi = lane >> 4;
    const int m0 = blockIdx.x * 128;
    const int n0 = blockIdx.y * 128;
    const int wm = (wid >> 1) * 64;
    const int wn = (wid & 1) * 64;

    const int srow = t >> 3;
    const int scol = ((t & 7) * 16) ^ ((srow & 7) << 4);

    const f32x4 zero4 = {0.f, 0.f, 0.f, 0.f};
    f32x4 acc[4][4];
#pragma unroll
    for (int i = 0; i < 4; ++i)
#pragma unroll
        for (int j = 0; j < 4; ++j) acc[i][j] = zero4;

    auto STAGE = [&](int buf, int k0) {
        char* As = smem + buf * 32768;
        char* Bs = As + 16384;
#pragma unroll
        for (int i = 0; i < 4; ++i) {
            const char* sa = (const char*)A + ((size_t)(m0 + i * 32 + srow) * NF + k0) * 2 + scol;
            load_lds16(sa, As + i * 4096 + wid * 1024);
            const char* sb = (const char*)WT + ((size_t)(n0 + i * 32 + srow) * NF + k0) * 2 + scol;
            load_lds16(sb, Bs + i * 4096 + wid * 1024);
        }
    };

    STAGE(0, 0);
    int cur = 0;
    for (int kt = 0; kt < 8; ++kt) {
        if (kt < 7) {
            STAGE(cur ^ 1, (kt + 1) * 64);  // prefetch next tile (8 loads/thread)
            asm volatile("s_waitcnt vmcnt(8)" ::: "memory");  // current tile landed
        } else {
            asm volatile("s_waitcnt vmcnt(0)" ::: "memory");
        }
        __builtin_amdgcn_s_barrier();
        __builtin_amdgcn_sched_barrier(0);

        const char* As = smem + cur * 32768;
        const char* Bs = As + 16384;
#pragma unroll
        for (int ks = 0; ks < 2; ++ks) {
            bf16x8 af[4], bfr[4];
#pragma unroll
            for (int i = 0; i < 4; ++i) {
                int ra = wm + i * 16 + l15;
                int ca = (ks * 64 + lhi * 16) ^ ((ra & 7) << 4);
                af[i] = *(const bf16x8*)(As + ra * 128 + ca);
                int rb = wn + i * 16 + l15;
                int cb = (ks * 64 + lhi * 16) ^ ((rb & 7) << 4);
                bfr[i] = *(const bf16x8*)(Bs + rb * 128 + cb);
            }
#pragma unroll
            for (int mi = 0; mi < 4; ++mi)
#pragma unroll
                for (int ni = 0; ni < 4; ++ni)
                    acc[mi][ni] = __builtin_amdgcn_mfma_f32_16x16x32_bf16(af[mi], bfr[ni], acc[mi][ni], 0, 0, 0);
        }
        __builtin_amdgcn_sched_barrier(0);
        __builtin_amdgcn_s_barrier();  // reads done before next overwrite
        cur ^= 1;
    }

    // epilogue: C/D layout col = lane&15, row = (lane>>4)*4 + reg
#pragma unroll
    for (int ni = 0; ni < 4; ++ni) {
        int col = n0 + wn + ni * 16 + l15;
        float bv2 = bias[col];
#pragma unroll
        for (int mi = 0; mi < 4; ++mi) {
#pragma unroll
            for (int r = 0; r < 4; ++r) {
                int row = m0 + wm + mi * 16 + lhi * 4 + r;
                float val = acc[mi][ni][r] + bv2;
                int b = row >> 12, s = row & (NS - 1);
                int hh = col >> 6, d = col & (ND - 1);
                if (mode == 0) {
                    val *= 0.1803368801111244f;  // (1/8) * log2(e): exp2-domain
                    Qh[((size_t)(b * NH + hh) * NS + s) * ND + d] = f2bf(val);
                } else if (mode == 1) {
                    Kh[((size_t)(b * NH + hh) * NS + s) * ND + d] = f2bf(val);
                } else {  // V transposed: [B,H,D,S]
                    VTs[((size_t)(b * NH + hh) * ND + d) * NS + s] = f2bf(val);
                }
            }
        }
    }
}

// Output projection: fp32 out, row-major [8192,512]. 64x128 tile (512 blocks),
// 2-phase double-buffered.
__launch_bounds__(256, 2)
__global__ void proj_o(const unsigned short* __restrict__ A,
                       const unsigned short* __restrict__ WT,
                       const float* __restrict__ bias,
                       float* __restrict__ Out) {
    __shared__ char smem[49152];  // 2 bufs x (A 8KB | B 16KB)

    const int t = threadIdx.x;
    const int wid = t >> 6;
    const int lane = t & 63;
    const int l15 = lane & 15;
    const int lhi = lane >> 4;
    const int m0 = blockIdx.x * 64;
    const int n0 = blockIdx.y * 128;
    const int wm = (wid >> 1) * 32;
    const int wn = (wid & 1) * 64;

    const int srow = t >> 3;
    const int scol = ((t & 7) * 16) ^ ((srow & 7) << 4);

    const f32x4 zero4 = {0.f, 0.f, 0.f, 0.f};
    f32x4 acc[2][4];
#pragma unroll
    for (int i = 0; i < 2; ++i)
#pragma unroll
        for (int j = 0; j < 4; ++j) acc[i][j] = zero4;

    auto STAGE = [&](int buf, int k0) {
        char* As = smem + buf * 24576;
        char* Bs = As + 8192;
#pragma unroll
        for (int i = 0; i < 2; ++i) {
            const char* sa = (const char*)A + ((size_t)(m0 + i * 32 + srow) * NF + k0) * 2 + scol;
            load_lds16(sa, As + i * 4096 + wid * 1024);
        }
#pragma unroll
        for (int i = 0; i < 4; ++i) {
            const char* sb = (const char*)WT + ((size_t)(n0 + i * 32 + srow) * NF + k0) * 2 + scol;
            load_lds16(sb, Bs + i * 4096 + wid * 1024);
        }
    };

    STAGE(0, 0);
    int cur = 0;
    for (int kt = 0; kt < 8; ++kt) {
        if (kt < 7) {
            STAGE(cur ^ 1, (kt + 1) * 64);  // 6 loads/thread
            asm volatile("s_waitcnt vmcnt(6)" ::: "memory");
        } else {
            asm volatile("s_waitcnt vmcnt(0)" ::: "memory");
        }
        __builtin_amdgcn_s_barrier();
        __builtin_amdgcn_sched_barrier(0);

        const char* As = smem + cur * 24576;
        const char* Bs = As + 8192;
#pragma unroll
        for (int ks = 0; ks < 2; ++ks) {
            bf16x8 af[2], bfr[4];
#pragma unroll
            for (int i = 0; i < 2; ++i) {
                int ra = wm + i * 16 + l15;
                int ca = (ks * 64 + lhi * 16) ^ ((ra & 7) << 4);
                af[i] = *(const bf16x8*)(As + ra * 128 + ca);
            }
#pragma unroll
            for (int i = 0; i < 4; ++i) {
                int rb = wn + i * 16 + l15;
                int cb = (ks * 64 + lhi * 16) ^ ((rb & 7) << 4);
                bfr[i] = *(const bf16x8*)(Bs + rb * 128 + cb);
            }
#pragma unroll
            for (int mi = 0; mi < 2; ++mi)
#pragma unroll
                for (int ni = 0; ni < 4; ++ni)
                    acc[mi][ni] = __builtin_amdgcn_mfma_f32_16x16x32_bf16(af[mi], bfr[ni], acc[mi][ni], 0, 0, 0);
        }
        __builtin_amdgcn_sched_barrier(0);
        __builtin_amdgcn_s_barrier();
        cur ^= 1;
    }

#pragma unroll
    for (int ni = 0; ni < 4; ++ni) {
        int col = n0 + wn + ni * 16 + l15;
        float bv2 = bias[col];
#pragma unroll
        for (int mi = 0; mi < 2; ++mi)
#pragma unroll
            for (int r = 0; r < 4; ++r) {
                int row = m0 + wm + mi * 16 + lhi * 4 + r;
                Out[(size_t)row * NF + col] = acc[mi][ni][r] + bv2;
            }
    }
}

// ---------------------------------------------------------------------------
// Fused causal flash attention — split-K (2 KV-halves per q-group), barrier-
// free, exp2-domain softmax. One WAVE per block (64 thr). 4096 blocks:
// k = blockIdx.x; pr = k&1 (KV half), kk = k>>1: bh = kk&15, g = 127-(kk>>4)
// (heavy-first). Wave owns 32 q rows, processes tiles [tbeg,tend) of 64 kv.
// Partials (m log2-domain, l, O bf16) -> workspace; attn_combine merges.
// launch_bounds (64,2): do NOT cap VGPRs harder — (64,4) forced a 64-VGPR
// allocation and ~1.2 GB of scratch spill traffic (r7). At ~104 VGPR the HW
// grants 4 waves/SIMD anyway (occupancy steps at 64/128/256).
// S^T = mfma(A=K, B=Q): D col = q = lane&31; row = kv = (r&3)+8*(r>>2)+4*h.
// P in registers (cvt_pk_bf16 pack + half-swap exchange -> PV B-fragments).
// O^T = mfma(A=V^T, B=P^T) with V pre-transposed [B,H,D,S].
__launch_bounds__(64, 2)
__global__ void attn_fused(const unsigned short* __restrict__ Qh,
                           const unsigned short* __restrict__ Kh,
                           const unsigned short* __restrict__ VT,
                           unsigned short* __restrict__ Op,   // [2][NROW][64] bf16
                           float* __restrict__ Mp,            // [2][NROW]
                           float* __restrict__ Lp) {          // [2][NROW]
    const int lane = threadIdx.x;  // 0..63
    const int l31 = lane & 31;
    const int h = lane >> 5;
    const int k = blockIdx.x;
    const int pr = k & 1;
    const int kk = k >> 1;
    const int bh = kk & 15;
    const int g = 127 - (kk >> 4);  // q-group (32 rows), heavy-first
    const int b = bh >> 3, hh = bh & 7;
    const size_t bhs = (size_t)b * NH + hh;
    const char* Qp = (const char*)(Qh + bhs * NS * ND);
    const char* Kp = (const char*)(Kh + bhs * NS * ND);
    const char* Vp = (const char*)(VT + bhs * (size_t)ND * NS);

    // Q fragments (B operand): Q[q=l31][16*kc + 8*h + j], contiguous 16B
    const int qrow = g * 32 + l31;
    bf16x8 qf[4];
#pragma unroll
    for (int kc = 0; kc < 4; ++kc)
        qf[kc] = *(const bf16x8*)(Qp + (size_t)qrow * 128 + kc * 32 + h * 16);

    f32x16 o[2];
#pragma unroll
    for (int r = 0; r < 16; ++r) { o[0][r] = 0.f; o[1][r] = 0.f; }
    float m_run = -1e30f, l_run = 0.f;

    const int nkv = (g >> 1) + 1;        // total KV tiles for this q-group
    const int hsp = (nkv + 1) >> 1;      // split point
    const int tbeg = pr ? hsp : 0;
    const int tend = pr ? nkv : hsp;

    // K fragments (A operand): kf[kvi*4+kc] = K[kv0+kvi*32+l31][kc*16+8h+:8]
    auto LOADK = [&](int t, bf16x8* kf) {
        const char* base = Kp + (size_t)t * 64 * 128;
#pragma unroll
        for (int kvi = 0; kvi < 2; ++kvi)
#pragma unroll
            for (int kc = 0; kc < 4; ++kc)
                kf[kvi * 4 + kc] = *(const bf16x8*)(base + (kvi * 32 + l31) * 128 + kc * 32 + h * 16);
    };
    // V fragments (A operand): vf[di*4+ck] = V^T[di*32+l31][kv0+ck*16+8h+:8]
    auto LOADV = [&](int t, bf16x8* vf) {
        const char* base = Vp + (size_t)t * 128;
#pragma unroll
        for (int di = 0; di < 2; ++di)
#pragma unroll
            for (int ck = 0; ck < 4; ++ck)
                vf[di * 4 + ck] = *(const bf16x8*)(base + (size_t)(di * 32 + l31) * (NS * 2) + ck * 32 + h * 16);
    };

    auto TILE = [&](int t, const bf16x8* kf, const bf16x8* vf) {
        // S^T = K @ Q^T (log2-domain scores: Q pre-scaled by log2e/8)
        f32x16 sT[2];
#pragma unroll
        for (int r = 0; r < 16; ++r) { sT[0][r] = 0.f; sT[1][r] = 0.f; }
#pragma unroll
        for (int kvi = 0; kvi < 2; ++kvi)
#pragma unroll
            for (int kc = 0; kc < 4; ++kc)
                sT[kvi] = __builtin_amdgcn_mfma_f32_32x32x16_bf16(kf[kvi * 4 + kc], qf[kc], sT[kvi], 0, 0, 0);

        // causal mask (the globally-last tile holds every row's diagonal)
        if (t == nkv - 1) {
#pragma unroll
            for (int kvi = 0; kvi < 2; ++kvi)
#pragma unroll
                for (int r = 0; r < 16; ++r) {
                    int kv = t * 64 + kvi * 32 + (r & 3) + ((r >> 2) << 3) + h * 4;
                    if (kv > qrow) sT[kvi][r] = -1e30f;
                }
        }

        // online softmax (base-2): lane owns one q; partner (xor 32) other 32 kv
        float pm = -1e30f;
#pragma unroll
        for (int kvi = 0; kvi < 2; ++kvi)
#pragma unroll
            for (int r = 0; r < 16; ++r) pm = fmaxf(pm, sT[kvi][r]);
        pm = fmaxf(pm, __shfl_xor(pm, 32));

        if (__ballot(pm > m_run + 11.5f) != 0ull) {  // defer-max (8 nats in bits)
            float mnew = fmaxf(m_run, pm);
            float sc = __builtin_amdgcn_exp2f(m_run - mnew);
            m_run = mnew;
            l_run *= sc;
#pragma unroll
            for (int di = 0; di < 2; ++di)
#pragma unroll
                for (int r = 0; r < 16; ++r) o[di][r] *= sc;
        }
        float rs = 0.f;
#pragma unroll
        for (int kvi = 0; kvi < 2; ++kvi)
#pragma unroll
            for (int r = 0; r < 16; ++r) {
                float p = __builtin_amdgcn_exp2f(sT[kvi][r] - m_run);
                sT[kvi][r] = p;
                rs += p;
            }
        rs += __shfl_xor(rs, 32);
        l_run += rs;

        // pack P via v_cvt_pk_bf16_f32; w[kvi][i] covers kv pair base
        // kvi*32 + 2*(i&1) + 8*(i>>1) + 4*h
        unsigned int w[2][8];
#pragma unroll
        for (int kvi = 0; kvi < 2; ++kvi)
#pragma unroll
            for (int i = 0; i < 8; ++i)
                w[kvi][i] = cvtpk(sT[kvi][2 * i], sT[kvi][2 * i + 1]);

        // exchange halves -> pf[ck]: element j = P[q=own][kv=16ck+8h+j];
        // each side CONTRIBUTES the word the other needs (value-select)
        union FB { unsigned int u[4]; bf16x8 v; };
        bf16x8 pf[4];
#pragma unroll
        for (int ck = 0; ck < 4; ++ck) {
            const int kvi = ck >> 1, pb = (ck & 1) * 4;
            unsigned int aSrc = h ? w[kvi][pb + 0] : w[kvi][pb + 2];
            unsigned int bSrc = h ? w[kvi][pb + 1] : w[kvi][pb + 3];
            unsigned int sA = (unsigned int)__shfl_xor((int)aSrc, 32);
            unsigned int sB = (unsigned int)__shfl_xor((int)bSrc, 32);
            FB f;
            f.u[0] = (h == 0) ? w[kvi][pb + 0] : sA;
            f.u[1] = (h == 0) ? w[kvi][pb + 1] : sB;
            f.u[2] = (h == 0) ? sA : w[kvi][pb + 2];
            f.u[3] = (h == 0) ? sB : w[kvi][pb + 3];
            pf[ck] = f.v;
        }

        // O^T += V^T @ P^T
#pragma unroll
        for (int di = 0; di < 2; ++di)
#pragma unroll
            for (int ck = 0; ck < 4; ++ck)
                o[di] = __builtin_amdgcn_mfma_f32_32x32x16_bf16(vf[di * 4 + ck], pf[ck], o[di], 0, 0, 0);
    };

    // ping-pong K sets (no runtime-indexed register arrays), JIT V
    if (tbeg < tend) {
        bf16x8 kA[8], kB[8], vv[8];
        LOADK(tbeg, kA);
        int t = tbeg;
        while (true) {
            LOADV(t, vv);
            if (t + 1 < tend) LOADK(t + 1, kB);
            TILE(t, kA, vv);
            if (++t >= tend) break;
            LOADV(t, vv);
            if (t + 1 < tend) LOADK(t + 1, kA);
            TILE(t, kB, vv);
            if (++t >= tend) break;
        }
    }

    // store partials: O bf16 (lane's d = 32*di + 8*tq + 4*h + r), m, l
    const int prow = bh * NS + qrow;
    size_t pb = ((size_t)pr * NROW + prow) * 64;
#pragma unroll
    for (int di = 0; di < 2; ++di)
#pragma unroll
        for (int tq = 0; tq < 4; ++tq) {
            uint2 pk;
            pk.x = cvtpk(o[di][4 * tq + 0], o[di][4 * tq + 1]);
            pk.y = cvtpk(o[di][4 * tq + 2], o[di][4 * tq + 3]);
            *(uint2*)(Op + pb + di * 32 + tq * 8 + h * 4) = pk;
        }
    if (h == 0) {
        Mp[pr * NROW + prow] = m_run;
        Lp[pr * NROW + prow] = l_run;
    }
}

// Merge the two KV-half partials: out = (O0*e0 + O1*e1) / (l0*e0 + l1*e1),
// e_i = exp2(m_i - max(m0,m1)). Writes concat [B,S,F] bf16. 1M threads x4 d.
__global__ void attn_combine(const unsigned short* __restrict__ Op,
                             const float* __restrict__ Mp, const float* __restrict__ Lp,
                             unsigned short* __restrict__ Cc) {
    int i = blockIdx.x * blockDim.x + threadIdx.x;  // NROW*16
    int row = i >> 4;
    int d4 = (i & 15) << 2;
    float m0 = Mp[row], m1 = Mp[NROW + row];
    float l0 = Lp[row], l1 = Lp[NROW + row];
    float m = fmaxf(m0, m1);
    float e0 = __builtin_amdgcn_exp2f(m0 - m);
    float e1 = __builtin_amdgcn_exp2f(m1 - m);
    float inv = 1.0f / (l0 * e0 + l1 * e1);
    e0 *= inv; e1 *= inv;
    ushort4 a = *(const ushort4*)(Op + (size_t)row * 64 + d4);
    ushort4 c = *(const ushort4*)(Op + (size_t)NROW * 64 + (size_t)row * 64 + d4);
    ushort4 r;
    r.x = f2bf(bf2f(a.x) * e0 + bf2f(c.x) * e1);
    r.y = f2bf(bf2f(a.y) * e0 + bf2f(c.y) * e1);
    r.z = f2bf(bf2f(a.z) * e0 + bf2f(c.z) * e1);
    r.w = f2bf(bf2f(a.w) * e0 + bf2f(c.w) * e1);
    int bb = row >> 15, hh = (row >> 12) & 7, s = row & (NS - 1);
    *(ushort4*)(Cc + ((size_t)(bb * NS + s) * NF) + hh * ND + d4) = r;
}

// ---------------------------------------------------------------------------
extern "C" void kernel_launch(void* const* d_in, const int* in_sizes, int n_in,
                              void* d_out, int out_size, void* d_ws, size_t ws_size,
                              hipStream_t stream) {
    const float* q = (const float*)d_in[0];
    const float* k = (const float*)d_in[1];
    const float* v = (const float*)d_in[2];
    // d_in[3] = mask (deterministic causal; applied analytically)
    const float* wq = (const float*)d_in[4];
    const float* bq = (const float*)d_in[5];
    const float* wk = (const float*)d_in[6];
    const float* bk = (const float*)d_in[7];
    const float* wv = (const float*)d_in[8];
    const float* bv = (const float*)d_in[9];
    const float* wo = (const float*)d_in[10];
    const float* bo = (const float*)d_in[11];

    const size_t MB = 1u << 20;
    char* ws = (char*)d_ws;
    unsigned short* qb  = (unsigned short*)(ws);             // 8MB (reused as concat)
    unsigned short* kb  = (unsigned short*)(ws + 8 * MB);    // 8MB  } reused as Opart
    unsigned short* vb  = (unsigned short*)(ws + 16 * MB);   // 8MB  } (16MB, 2xNROWx64 bf16)
    unsigned short* wqT = (unsigned short*)(ws + 24 * MB);           // } reused as Mp/Lp
    unsigned short* wkT = (unsigned short*)(ws + 24 * MB + 512 * 1024);
    unsigned short* wvT = (unsigned short*)(ws + 25 * MB);
    unsigned short* woT = (unsigned short*)(ws + 25 * MB + 512 * 1024);  // kept for proj_o
    unsigned short* Qh  = (unsigned short*)(ws + 26 * MB);   // 8MB [B,H,S,D] pre-scaled
    unsigned short* Kh  = (unsigned short*)(ws + 34 * MB);   // 8MB [B,H,S,D]
    unsigned short* VTs = (unsigned short*)(ws + 42 * MB);   // 8MB [B,H,D,S]

    unsigned short* Opart = kb;                        // 16MB, dead kb+vb
    float* Mpart = (float*)(ws + 24 * MB);             // 512KB over dead wqT
    float* Lpart = (float*)(ws + 24 * MB + 512 * 1024);// 512KB over dead wkT

    convert_all<<<dim3(2048), dim3(256), 0, stream>>>(q, k, v, qb, kb, vb,
                                                      wq, wk, wv, wo, wqT, wkT, wvT, woT);

    proj_qkv<<<dim3(NM / 128, NF / 128, 3), dim3(256), 0, stream>>>(
        qb, kb, vb, wqT, wkT, wvT, bq, bk, bv, Qh, Kh, VTs);

    attn_fused<<<dim3(4096), dim3(64), 0, stream>>>(Qh, Kh, VTs, Opart, Mpart, Lpart);

    attn_combine<<<dim3(NROW * 16 / 256), dim3(256), 0, stream>>>(Opart, Mpart, Lpart, qb);

    proj_o<<<dim3(NM / 64, NF / 128), dim3(256), 0, stream>>>(qb, woT, bo, (float*)d_out);
}